// Round 11
// baseline (351.044 us; speedup 1.0000x reference)
//
#include <hip/hip_runtime.h>
#include <hip/hip_bf16.h>

#define B_      2048
#define R_      333
#define MAXI_   119
#define MAXO_   12
#define CONCAT_ 3325
#define E_      3328
#define TOTAL_  24696
#define HID_    1024
#define NREG_   300
#define NCLS_   180
#define EPS_    1e-5f
#define NSLOT_  128
#define PSTR_   3328
#define NS2_    128

typedef __attribute__((ext_vector_type(8))) short bf16x8;
typedef __attribute__((ext_vector_type(4))) float f32x4;

static __device__ inline unsigned short f2bf_rne(float f) {
  unsigned u;
  __builtin_memcpy(&u, &f, 4);
  u += 0x7fff + ((u >> 16) & 1);
  return (unsigned short)(u >> 16);
}
static __device__ inline float bf2f(unsigned short s) {
  unsigned u = (unsigned)s << 16;
  float f;
  __builtin_memcpy(&f, &u, 4);
  return f;
}

// ---------------- layout ----------------
__global__ void layout_kernel(int* __restrict__ starts, int* __restrict__ red_starts) {
  if (threadIdx.x == 0 && blockIdx.x == 0) {
    int s = 0, rs = 0;
    for (int r = 0; r < R_; ++r) {
      starts[r] = s;
      red_starts[r] = rs;
      s += 30 + (7 * r) % 90;
      rs += (r == 332) ? 8 : (8 + r % 5);
    }
  }
}

// ---------------- rowdot body: out[j] = A[j,:].v + b[j] (f32 exact) ----------------
__device__ __forceinline__ void rowdot_body(
    const float* __restrict__ A, const float* __restrict__ v, const float* __restrict__ b,
    float* __restrict__ out, int N, int K, int jb) {
  int wid = threadIdx.x >> 6, lane = threadIdx.x & 63;
  int j = jb * 4 + wid;
  if (j >= N) return;
  const float* row = A + (size_t)j * K;
  float s = 0.f;
  for (int k = lane; k < K; k += 64) s = fmaf(row[k], v[k], s);
  for (int o = 32; o; o >>= 1) s += __shfl_down(s, o);
  if (lane == 0) out[j] = s + b[j];
}

// ---------------- pack enc_W body (alignment shift baked in) ----------------
__device__ __forceinline__ void pack_w_body(const float* __restrict__ enc_W,
                                            const int* __restrict__ starts,
                                            unsigned short* __restrict__ Wpk, int r) {
  int tid = threadIdx.x;
  int kc = tid >> 6, lane = tid & 63;
  int size = 30 + (7 * r) % 90;
  int s8 = starts[r] & 7;
  int oc = lane & 15;
  int k0 = kc * 32 + (lane >> 4) * 8;
  unsigned short o[8];
#pragma unroll
  for (int e = 0; e < 8; ++e) {
    int k = k0 + e - s8;
    float v = 0.f;
    if (oc < MAXO_ && k >= 0 && k < size) v = enc_W[((size_t)r * MAXO_ + oc) * MAXI_ + k];
    o[e] = f2bf_rne(v);
  }
  unsigned short* dst = Wpk + ((size_t)r * 4 + kc) * 512 + lane * 8;
  *(ushort4*)dst = *(ushort4*)&o[0];
  *(ushort4*)(dst + 4) = *(ushort4*)&o[4];
}

// ---------------- K2: pack_w (333) + rowdot1 t1=Wo*bv+bo (832) ----------------
__global__ __launch_bounds__(256) void packw_rd1_kernel(
    const float* __restrict__ enc_W, const int* __restrict__ starts,
    unsigned short* __restrict__ Wpk,
    const float* __restrict__ Wo, const float* __restrict__ bv,
    const float* __restrict__ bo, float* __restrict__ t1v) {
  int bid = blockIdx.x;
  if (bid < R_) pack_w_body(enc_W, starts, Wpk, bid);
  else          rowdot_body(Wo, bv, bo, t1v, E_, E_, bid - R_);
}

// ---------------- encoder body: 1-tile lean (VGPR ~52), zero LDS ----------------
__device__ __forceinline__ void encode_body(
    const float* __restrict__ x, const unsigned short* __restrict__ Wpk,
    const float* __restrict__ enc_b, const int* __restrict__ starts,
    const int* __restrict__ red_starts,
    unsigned short* __restrict__ yT, float* __restrict__ pS1, float* __restrict__ pS2,
    int r, int bg) {
  int tid = threadIdx.x;
  int wid = tid >> 6, lane = tid & 63;
  int lr = lane & 15, kg = lane >> 4;

  int size = 30 + (7 * r) % 90;
  int red  = (r == 332) ? 8 : (8 + r % 5);
  int st   = starts[r];
  int s8   = st & 7;
  int a0   = st & ~7;
  int rs   = red_starts[r];
  int nkc  = (s8 + size + 31) >> 5;
  int kmax = TOTAL_ - a0;

  bf16x8 wf[4];
  const unsigned short* wp = Wpk + (size_t)r * 2048 + lane * 8;
#pragma unroll
  for (int kc = 0; kc < 4; ++kc) wf[kc] = *(const bf16x8*)(wp + kc * 512);

  float bofs[4];
#pragma unroll
  for (int reg = 0; reg < 4; ++reg) {
    int oc = kg * 4 + reg;
    bofs[reg] = (oc < MAXO_) ? enc_b[r * MAXO_ + oc] : 0.f;
  }

  for (int t = 0; t < 4; ++t) {
    int b0 = bg * 256 + wid * 64 + t * 16;
    const float* xrow = x + (size_t)(b0 + lr) * TOTAL_ + a0;
    f32x4 acc = {0.f, 0.f, 0.f, 0.f};
#pragma unroll
    for (int kc = 0; kc < 4; ++kc) {
      if (kc < nkc) {
        int k0 = kc * 32 + kg * 8;
        if (k0 + 8 > kmax) k0 = kmax - 8;   // only all-zero-weight frags clamp
        float4 v0 = *(const float4*)(xrow + k0);
        float4 v1 = *(const float4*)(xrow + k0 + 4);
        bf16x8 xf;
        xf[0] = (short)f2bf_rne(v0.x); xf[1] = (short)f2bf_rne(v0.y);
        xf[2] = (short)f2bf_rne(v0.z); xf[3] = (short)f2bf_rne(v0.w);
        xf[4] = (short)f2bf_rne(v1.x); xf[5] = (short)f2bf_rne(v1.y);
        xf[6] = (short)f2bf_rne(v1.z); xf[7] = (short)f2bf_rne(v1.w);
        acc = __builtin_amdgcn_mfma_f32_16x16x32_bf16(wf[kc], xf, acc, 0, 0, 0);
      }
    }
    int slot = b0 >> 4;
#pragma unroll
    for (int reg = 0; reg < 4; ++reg) {
      int oc = kg * 4 + reg;
      if (oc < red) {
        float v = acc[reg] + bofs[reg];
        yT[(size_t)(rs + oc) * B_ + b0 + lr] = f2bf_rne(v);
        float a = v, s2 = v * v;
#pragma unroll
        for (int m = 1; m <= 8; m <<= 1) { a += __shfl_xor(a, m); s2 += __shfl_xor(s2, m); }
        if (lr == 0) {
          pS1[slot * PSTR_ + rs + oc] = a;
          pS2[slot * PSTR_ + rs + oc] = s2;
        }
      }
    }
  }
}

// ---------------- K3 "grand": encode || transposes || casts || rowdot2 ----------------
// All memory-streaming / latency-bound work, lean resource envelope (16.6KB LDS, ~52 VGPR)
// so encode blocks keep high occupancy. GEMMs live in separate kernels.
#define ENC_NB_ (R_ * 8)                              // 2664
#define NTR_    ((E_ / 64) * (E_ / 64))               // 2704 per matrix
#define NC4A_   (HID_ * E_ / 4)
#define NC4B_   (NREG_ * HID_ / 4)
#define NCAST_  ((NC4A_ + NC4B_ + 255) / 256)         // 3628
__global__ __launch_bounds__(256) void grand_kernel(
    const float* __restrict__ x, const unsigned short* __restrict__ Wpk,
    const float* __restrict__ enc_b, const int* __restrict__ starts,
    const int* __restrict__ red_starts,
    unsigned short* __restrict__ yT, float* __restrict__ pS1, float* __restrict__ pS2,
    const float* __restrict__ Wo, const float* __restrict__ Wv,
    unsigned short* __restrict__ WoT, unsigned short* __restrict__ WvT,
    const float* __restrict__ W1, unsigned short* __restrict__ W1b,
    const float* __restrict__ W2, unsigned short* __restrict__ W2b,
    const float* __restrict__ t1v, const float* __restrict__ b1, float* __restrict__ zbv) {
  __shared__ float tile[64][65];
  int bid = blockIdx.x;
  if (bid < ENC_NB_) {
    encode_body(x, Wpk, enc_b, starts, red_starts, yT, pS1, pS2, bid >> 3, bid & 7);
  } else if (bid < ENC_NB_ + 2 * NTR_) {
    int tb = bid - ENC_NB_;
    int z = tb / NTR_, rem = tb % NTR_;
    const float* in = z ? Wv : Wo;
    unsigned short* out = z ? WvT : WoT;
    int c0 = (rem % 52) * 64, r0 = (rem / 52) * 64;
    int t = threadIdx.x;
    int ci = t & 63, ri0 = t >> 6;
    for (int ri = ri0; ri < 64; ri += 4)
      tile[ri][ci] = in[(size_t)(r0 + ri) * E_ + c0 + ci];
    __syncthreads();
    int rj = t & 63, i0 = t >> 6;
    for (int i = i0; i < 64; i += 4)
      out[(size_t)(c0 + i) * E_ + r0 + rj] = f2bf_rne(tile[rj][i]);
  } else if (bid < ENC_NB_ + 2 * NTR_ + NCAST_) {
    int i = (bid - ENC_NB_ - 2 * NTR_) * 256 + threadIdx.x;
    const float* src; unsigned short* dst; int idx;
    if (i < NC4A_) { src = W1; dst = W1b; idx = i; }
    else if (i < NC4A_ + NC4B_) { src = W2; dst = W2b; idx = i - NC4A_; }
    else return;
    float4 v = ((const float4*)src)[idx];
    ushort4 o;
    o.x = f2bf_rne(v.x); o.y = f2bf_rne(v.y); o.z = f2bf_rne(v.z); o.w = f2bf_rne(v.w);
    ((ushort4*)dst)[idx] = o;
  } else {
    rowdot_body(W1, t1v, b1, zbv, HID_, E_, bid - ENC_NB_ - 2 * NTR_ - NCAST_);
  }
}

// ---------------- GEMM body: 128x128 tile, BK=32, dbuf 2-phase, optional split-K ------
template <int KS, bool OUT_BF16>
__device__ __forceinline__ void gemm_body(
    const unsigned short* __restrict__ A, const unsigned short* __restrict__ W,
    float* __restrict__ Cf, unsigned short* __restrict__ Cb,
    int M, int N, int K, int bx, int by, int bz, unsigned short* smem) {
  unsigned short* a_lds = smem;
  unsigned short* b_lds = smem + 8192;
  int tid = threadIdx.x;
  int wid = tid >> 6, lane = tid & 63;
  int wr = wid >> 1, wc = wid & 1;
  int row0 = by * 128, col0 = bx * 128;
  int lr = lane & 15, kg = lane >> 4;
  int Klocal = K / KS;
  int kbase = bz * Klocal;

  int srow = tid >> 2, sk = (tid & 3) * 8;
  const unsigned short* aptr0 = A + (size_t)(row0 + srow) * K + kbase + sk;
  const unsigned short* aptr1 = aptr0 + (size_t)64 * K;
  int bcol0 = col0 + srow;      if (bcol0 > N - 1) bcol0 = N - 1;
  int bcol1 = col0 + 64 + srow; if (bcol1 > N - 1) bcol1 = N - 1;
  const unsigned short* bptr0 = W + (size_t)bcol0 * K + kbase + sk;
  const unsigned short* bptr1 = W + (size_t)bcol1 * K + kbase + sk;

  f32x4 acc[4][4] = {};
  int nk = Klocal >> 5;

#define STAGE_(buf, kc)                                                                             \
  do {                                                                                              \
    __builtin_amdgcn_global_load_lds((const __attribute__((address_space(1))) void*)(aptr0 + (kc)), \
        (__attribute__((address_space(3))) void*)(a_lds + (buf) * 4096 + wid * 512), 16, 0, 0);     \
    __builtin_amdgcn_global_load_lds((const __attribute__((address_space(1))) void*)(aptr1 + (kc)), \
        (__attribute__((address_space(3))) void*)(a_lds + (buf) * 4096 + 2048 + wid * 512), 16, 0, 0); \
    __builtin_amdgcn_global_load_lds((const __attribute__((address_space(1))) void*)(bptr0 + (kc)), \
        (__attribute__((address_space(3))) void*)(b_lds + (buf) * 4096 + wid * 512), 16, 0, 0);     \
    __builtin_amdgcn_global_load_lds((const __attribute__((address_space(1))) void*)(bptr1 + (kc)), \
        (__attribute__((address_space(3))) void*)(b_lds + (buf) * 4096 + 2048 + wid * 512), 16, 0, 0); \
  } while (0)

  STAGE_(0, 0);
  __syncthreads();
  int cur = 0;
  for (int t = 0; t < nk; ++t) {
    if (t + 1 < nk) STAGE_(cur ^ 1, (t + 1) * 32);
    bf16x8 a[4], b[4];
#pragma unroll
    for (int f = 0; f < 4; ++f) {
      a[f] = *(const bf16x8*)(a_lds + cur * 4096 + (wr * 64 + f * 16 + lr) * 32 + kg * 8);
      b[f] = *(const bf16x8*)(b_lds + cur * 4096 + (wc * 64 + f * 16 + lr) * 32 + kg * 8);
    }
#pragma unroll
    for (int i = 0; i < 4; ++i)
#pragma unroll
      for (int j = 0; j < 4; ++j)
        acc[i][j] = __builtin_amdgcn_mfma_f32_16x16x32_bf16(a[i], b[j], acc[i][j], 0, 0, 0);
    __syncthreads();
    cur ^= 1;
  }
#undef STAGE_

#pragma unroll
  for (int j = 0; j < 4; ++j) {
    int ccol = col0 + wc * 64 + j * 16 + lr;
    if (ccol >= N) continue;
#pragma unroll
    for (int i = 0; i < 4; ++i) {
#pragma unroll
      for (int reg = 0; reg < 4; ++reg) {
        int crow = row0 + wr * 64 + i * 16 + kg * 4 + reg;
        float v = acc[i][j][reg];
        if (KS == 1) {
          if (OUT_BF16) Cb[(size_t)crow * N + ccol] = f2bf_rne(v);
          else          Cf[(size_t)crow * N + ccol] = v;
        } else {
          Cf[((size_t)bz * M + crow) * N + ccol] = v;
        }
      }
    }
  }
}

// ---------------- K4: Wa = W1*Wo (208, bf16 direct) || bn1_stats (13) ----------------
#define WA_NB_ ((E_ / 128) * (HID_ / 128))   // 208
__global__ __launch_bounds__(256) void wa_stats_kernel(
    const unsigned short* __restrict__ W1b, const unsigned short* __restrict__ WoT,
    unsigned short* __restrict__ Wa_bf,
    const float* __restrict__ pS1, const float* __restrict__ pS2,
    float* __restrict__ mean, float* __restrict__ rstd) {
  __shared__ __align__(16) unsigned short smem[16384];
  int bid = blockIdx.x;
  if (bid < WA_NB_) {
    gemm_body<1, true>(W1b, WoT, nullptr, Wa_bf, HID_, E_, E_,
                       bid % (E_ / 128), bid / (E_ / 128), 0, smem);
  } else {
    int c = (bid - WA_NB_) * 256 + threadIdx.x;
    if (c >= CONCAT_) return;
    float s = 0.f, s2 = 0.f;
    for (int i = 0; i < NSLOT_; ++i) { s += pS1[i * PSTR_ + c]; s2 += pS2[i * PSTR_ + c]; }
    float m = s / B_;
    float v = s2 / B_ - m * m;
    mean[c] = m;
    rstd[c] = rsqrtf(v + EPS_);
  }
}

// ---------------- K5: Wb = Wa*Wv (KS=1, 208, bf16 direct) || bn1_transpose+pad (1664) --
#define TR_NB_ ((E_ / 64) * (B_ / 64))       // 1664
__global__ __launch_bounds__(256) void trans_wb_kernel(
    const unsigned short* __restrict__ yT, const float* __restrict__ mean,
    const float* __restrict__ rstd, const float* __restrict__ g,
    const float* __restrict__ bb, unsigned short* __restrict__ Y,
    const unsigned short* __restrict__ Wa_bf, const unsigned short* __restrict__ WvT,
    unsigned short* __restrict__ Wb_bf) {
  __shared__ __align__(16) unsigned short smem[16384];
  int bid = blockIdx.x;
  if (bid < WA_NB_) {
    gemm_body<1, true>(Wa_bf, WvT, nullptr, Wb_bf, HID_, E_, E_,
                       bid % (E_ / 128), bid / (E_ / 128), 0, smem);
  } else {
    int tb = bid - WA_NB_;
    int cc0 = (tb % 52) * 64, b0 = (tb / 52) * 64;
    float (*tile)[65] = (float(*)[65])smem;
    int t = threadIdx.x;
    int bi = t & 63, ci0 = t >> 6;
    for (int ci = ci0; ci < 64; ci += 4) {
      int c = cc0 + ci - 1;              // F.pad(1,2): output col cc -> feature cc-1
      float v = 0.f;
      if (c >= 0 && c < CONCAT_) {
        float f = bf2f(yT[(size_t)c * B_ + b0 + bi]);
        v = (f - mean[c]) * rstd[c] * g[c] + bb[c];
        v = v > 0.f ? v : 0.3f * v;
      }
      tile[ci][bi] = v;
    }
    __syncthreads();
    int cj = t & 63, bj0 = t >> 6;
    for (int bj = bj0; bj < 64; bj += 4)
      Y[(size_t)(b0 + bj) * E_ + cc0 + cj] = f2bf_rne(tile[cj][bj]);
  }
}

// ---------------- standalone GEMM wrapper ----------------
template <int KS, bool OUT_BF16>
__global__ __launch_bounds__(256) void gemm_kernel(
    const unsigned short* __restrict__ A, const unsigned short* __restrict__ W,
    float* __restrict__ Cf, unsigned short* __restrict__ Cb, int M, int N, int K) {
  __shared__ __align__(16) unsigned short smem[16384];
  gemm_body<KS, OUT_BF16>(A, W, Cf, Cb, M, N, K, blockIdx.x, blockIdx.y, blockIdx.z, smem);
}

// ---------------- fused: Z combine (4 slices + zb) + BN2 partial stats ----------------
__global__ __launch_bounds__(256) void combZ_stats_kernel(
    const float* __restrict__ Cpart, const float* __restrict__ zb,
    float* __restrict__ Z, float* __restrict__ pS, float* __restrict__ pS2) {
  int c = blockIdx.x * 256 + threadIdx.x;
  int ry = blockIdx.y;
  float zbc = zb[c];
  float s1 = 0.f, s2 = 0.f;
  for (int r = ry * 16; r < ry * 16 + 16; ++r) {
    float v = zbc;
#pragma unroll
    for (int z = 0; z < 4; ++z) v += Cpart[((size_t)z * B_ + r) * HID_ + c];
    Z[(size_t)r * HID_ + c] = v;
    s1 += v; s2 = fmaf(v, v, s2);
  }
  pS[ry * HID_ + c] = s1;
  pS2[ry * HID_ + c] = s2;
}

__global__ __launch_bounds__(256) void colstats_final_kernel(
    const float* __restrict__ pS, const float* __restrict__ pS2,
    float* __restrict__ mean, float* __restrict__ rstd) {
  int c = blockIdx.x * 256 + threadIdx.x;
  if (c >= HID_) return;
  float s = 0.f, s2 = 0.f;
  for (int i = 0; i < NS2_; ++i) { s += pS[i * HID_ + c]; s2 += pS2[i * HID_ + c]; }
  float m = s / B_;
  float v = s2 / B_ - m * m;
  mean[c] = m;
  rstd[c] = rsqrtf(v + EPS_);
}

// ---------------- BN2 apply + LeakyReLU(0.1) -> bf16 ----------------
__global__ __launch_bounds__(256) void bn2_apply_kernel(
    const float* __restrict__ Z, const float* __restrict__ mean, const float* __restrict__ rstd,
    const float* __restrict__ g, const float* __restrict__ bb, unsigned short* __restrict__ R) {
  int i = blockIdx.x * 256 + threadIdx.x;
  int c = i & (HID_ - 1);
  float v = (Z[i] - mean[c]) * rstd[c] * g[c] + bb[c];
  v = v > 0.f ? v : 0.1f * v;
  R[i] = f2bf_rne(v);
}

// ---------------- classifier with fused W2 split-K combine ----------------
__global__ __launch_bounds__(256) void classifier_kernel(
    const float* __restrict__ Cpart, const float* __restrict__ b2,
    const float* __restrict__ Wc, const float* __restrict__ bc,
    float* __restrict__ reg_out, float* __restrict__ ypred) {
  int b = blockIdx.x;
  __shared__ __align__(16) float rrow[NREG_];
  __shared__ float sl[256];
  int tid = threadIdx.x;
  for (int i = tid; i < NREG_; i += 256) {
    float s = b2[i];
#pragma unroll
    for (int z = 0; z < 4; ++z) s += Cpart[((size_t)z * B_ + b) * NREG_ + i];
    rrow[i] = s;
    reg_out[(size_t)b * NREG_ + i] = s;
  }
  __syncthreads();
  float s = -1e30f;
  if (tid < NCLS_) {
    const float* w = Wc + (size_t)tid * NREG_;
    float acc = 0.f;
    for (int k = 0; k < NREG_; k += 4) {
      float4 wv = *(const float4*)(w + k);
      float4 rv = *(const float4*)(&rrow[k]);
      acc = fmaf(wv.x, rv.x, acc); acc = fmaf(wv.y, rv.y, acc);
      acc = fmaf(wv.z, rv.z, acc); acc = fmaf(wv.w, rv.w, acc);
    }
    s = acc + bc[tid];
  }
  sl[tid] = s;
  __syncthreads();
  for (int o = 128; o > 0; o >>= 1) {
    if (tid < o) sl[tid] = fmaxf(sl[tid], sl[tid + o]);
    __syncthreads();
  }
  float mx = sl[0];
  __syncthreads();
  float e = (tid < NCLS_) ? __expf(s - mx) : 0.f;
  sl[tid] = e;
  __syncthreads();
  for (int o = 128; o > 0; o >>= 1) {
    if (tid < o) sl[tid] += sl[tid + o];
    __syncthreads();
  }
  if (tid < NCLS_) ypred[(size_t)b * NCLS_ + tid] = e / sl[0];
}

// ---------------- host orchestration ----------------
extern "C" void kernel_launch(void* const* d_in, const int* in_sizes, int n_in,
                              void* d_out, int out_size, void* d_ws, size_t ws_size,
                              hipStream_t stream) {
  const float* x     = (const float*)d_in[0];
  const float* enc_W = (const float*)d_in[1];
  const float* enc_b = (const float*)d_in[2];
  const float* bn1_g = (const float*)d_in[3];
  const float* bn1_b = (const float*)d_in[4];
  const float* Wqkv  = (const float*)d_in[5];
  const float* bqkv  = (const float*)d_in[6];
  const float* Wo    = (const float*)d_in[7];
  const float* bo    = (const float*)d_in[8];
  const float* W1    = (const float*)d_in[9];
  const float* b1    = (const float*)d_in[10];
  const float* bn2_g = (const float*)d_in[11];
  const float* bn2_b = (const float*)d_in[12];
  const float* W2    = (const float*)d_in[13];
  const float* b2    = (const float*)d_in[14];
  const float* Wc    = (const float*)d_in[15];
  const float* bc    = (const float*)d_in[16];

  char* ws = (char*)d_ws;
  size_t off = 0;
  auto alloc = [&](size_t bytes) -> void* {
    void* p = ws + off;
    off += (bytes + 255) & ~(size_t)255;
    return p;
  };

  unsigned short* yT     = (unsigned short*)alloc((size_t)CONCAT_ * B_ * 2); // bf16; reused for Z(f32)
  float*          pS1b   = (float*)alloc((size_t)NSLOT_ * PSTR_ * 4);
  float*          pS2b   = (float*)alloc((size_t)NSLOT_ * PSTR_ * 4);
  float*          mean1  = (float*)alloc(CONCAT_ * 4);
  float*          rstd1  = (float*)alloc(CONCAT_ * 4);
  unsigned short* Ybf    = (unsigned short*)alloc((size_t)B_ * E_ * 2);
  unsigned short* Rbf    = (unsigned short*)alloc((size_t)B_ * HID_ * 2);
  unsigned short* WoT_bf = (unsigned short*)alloc((size_t)E_ * E_ * 2);
  unsigned short* WvT_bf = (unsigned short*)alloc((size_t)E_ * E_ * 2);
  unsigned short* W1_bf  = (unsigned short*)alloc((size_t)HID_ * E_ * 2);
  unsigned short* W2_bf  = (unsigned short*)alloc((size_t)NREG_ * HID_ * 2);
  unsigned short* Wa_bf  = (unsigned short*)alloc((size_t)HID_ * E_ * 2);
  unsigned short* Wb_bf  = (unsigned short*)alloc((size_t)HID_ * E_ * 2);
  unsigned short* Wpk    = (unsigned short*)alloc((size_t)R_ * 2048 * 2);
  float*          Cpart  = (float*)alloc((size_t)4 * B_ * HID_ * 4);
  float*          t1v    = (float*)alloc(E_ * 4);
  float*          zbv    = (float*)alloc(HID_ * 4);
  float*          partS  = (float*)alloc((size_t)NS2_ * HID_ * 4);
  float*          partS2 = (float*)alloc((size_t)NS2_ * HID_ * 4);
  float*          mean2  = (float*)alloc(HID_ * 4);
  float*          rstd2  = (float*)alloc(HID_ * 4);
  int*            starts = (int*)alloc(R_ * 4);
  int*            redst  = (int*)alloc(R_ * 4);

  float* Z = (float*)yT;

  // K1: layout
  layout_kernel<<<1, 1, 0, stream>>>(starts, redst);
  // K2: pack_w + rowdot1 (t1 = Wo*bv + bo)
  packw_rd1_kernel<<<R_ + E_ / 4, 256, 0, stream>>>(
      enc_W, starts, Wpk, Wo, bqkv + 2 * E_, bo, t1v);
  // K3 grand: encode || transposes(Wo,Wv) || casts(W1,W2) || rowdot2 (zb)
  grand_kernel<<<ENC_NB_ + 2 * NTR_ + NCAST_ + HID_ / 4, 256, 0, stream>>>(
      x, Wpk, enc_b, starts, redst, yT, pS1b, pS2b,
      Wo, Wqkv + (size_t)2 * E_ * E_, WoT_bf, WvT_bf,
      W1, W1_bf, W2, W2_bf, t1v, b1, zbv);
  // K4: Wa = W1*Wo (bf16 direct) || bn1_stats
  wa_stats_kernel<<<WA_NB_ + (CONCAT_ + 255) / 256, 256, 0, stream>>>(
      W1_bf, WoT_bf, Wa_bf, pS1b, pS2b, mean1, rstd1);
  // K5: Wb = Wa*Wv (bf16 direct) || BN1 apply+transpose+pad
  trans_wb_kernel<<<WA_NB_ + TR_NB_, 256, 0, stream>>>(
      yT, mean1, rstd1, bn1_g, bn1_b, Ybf, Wa_bf, WvT_bf, Wb_bf);
  // K6: Z = Y @ Wb^T (KS=4)
  gemm_kernel<4, false><<<dim3(HID_ / 128, B_ / 128, 4), 256, 0, stream>>>(
      Ybf, Wb_bf, Cpart, nullptr, B_, HID_, E_);
  // K7: Z combine + zb + BN2 partial stats
  combZ_stats_kernel<<<dim3(HID_ / 256, NS2_), 256, 0, stream>>>(Cpart, zbv, Z, partS, partS2);
  // K8: BN2 stats finalize
  colstats_final_kernel<<<(HID_ + 255) / 256, 256, 0, stream>>>(partS, partS2, mean2, rstd2);
  // K9: BN2 apply -> bf16
  bn2_apply_kernel<<<(B_ * HID_) / 256, 256, 0, stream>>>(Z, mean2, rstd2, bn2_g, bn2_b, Rbf);
  // K10: reg partials: R @ W2^T (KS=4)
  gemm_kernel<4, false><<<dim3((NREG_ + 127) / 128, B_ / 128, 4), 256, 0, stream>>>(
      Rbf, W2_bf, Cpart, nullptr, B_, NREG_, HID_);
  // K11: classifier (fused W2 combine) -> reg_out, y_pred
  float* reg_out = (float*)d_out;
  classifier_kernel<<<B_, 256, 0, stream>>>(
      Cpart, b2, Wc, bc, reg_out, reg_out + (size_t)B_ * NREG_);
}

// Round 12
// 313.618 us; speedup vs baseline: 1.1193x; 1.1193x over previous
//
#include <hip/hip_runtime.h>
#include <hip/hip_bf16.h>

#define B_      2048
#define R_      333
#define MAXI_   119
#define MAXO_   12
#define CONCAT_ 3325
#define E_      3328
#define TOTAL_  24696
#define HID_    1024
#define NREG_   300
#define NCLS_   180
#define EPS_    1e-5f
#define NS2_    128

typedef __attribute__((ext_vector_type(8))) short bf16x8;
typedef __attribute__((ext_vector_type(4))) float f32x4;

static __device__ inline unsigned short f2bf_rne(float f) {
  unsigned u;
  __builtin_memcpy(&u, &f, 4);
  u += 0x7fff + ((u >> 16) & 1);
  return (unsigned short)(u >> 16);
}
static __device__ inline float bf2f(unsigned short s) {
  unsigned u = (unsigned)s << 16;
  float f;
  __builtin_memcpy(&f, &u, 4);
  return f;
}

// ---------------- layout ----------------
__global__ void layout_kernel(int* __restrict__ starts, int* __restrict__ red_starts) {
  if (threadIdx.x == 0 && blockIdx.x == 0) {
    int s = 0, rs = 0;
    for (int r = 0; r < R_; ++r) {
      starts[r] = s;
      red_starts[r] = rs;
      s += 30 + (7 * r) % 90;
      rs += (r == 332) ? 8 : (8 + r % 5);
    }
  }
}

// ---------------- rowdot body: out[j] = A[j,:].v + b[j] (f32 exact) ----------------
__device__ __forceinline__ void rowdot_body(
    const float* __restrict__ A, const float* __restrict__ v, const float* __restrict__ b,
    float* __restrict__ out, int N, int K, int jb) {
  int wid = threadIdx.x >> 6, lane = threadIdx.x & 63;
  int j = jb * 4 + wid;
  if (j >= N) return;
  const float* row = A + (size_t)j * K;
  float s = 0.f;
  for (int k = lane; k < K; k += 64) s = fmaf(row[k], v[k], s);
  for (int o = 32; o; o >>= 1) s += __shfl_down(s, o);
  if (lane == 0) out[j] = s + b[j];
}

// ---------------- pack enc_W body (alignment shift baked in) ----------------
__device__ __forceinline__ void pack_w_body(const float* __restrict__ enc_W,
                                            const int* __restrict__ starts,
                                            unsigned short* __restrict__ Wpk, int r) {
  int tid = threadIdx.x;
  int kc = tid >> 6, lane = tid & 63;
  int size = 30 + (7 * r) % 90;
  int s8 = starts[r] & 7;
  int oc = lane & 15;
  int k0 = kc * 32 + (lane >> 4) * 8;
  unsigned short o[8];
#pragma unroll
  for (int e = 0; e < 8; ++e) {
    int k = k0 + e - s8;
    float v = 0.f;
    if (oc < MAXO_ && k >= 0 && k < size) v = enc_W[((size_t)r * MAXO_ + oc) * MAXI_ + k];
    o[e] = f2bf_rne(v);
  }
  unsigned short* dst = Wpk + ((size_t)r * 4 + kc) * 512 + lane * 8;
  *(ushort4*)dst = *(ushort4*)&o[0];
  *(ushort4*)(dst + 4) = *(ushort4*)&o[4];
}

// ---------------- K2 prep: transposes(Wo,Wv) || casts(W1,W2) || rowdot1 || pack_w -----
#define NTR_    ((E_ / 64) * (E_ / 64))               // 2704 per matrix
#define NC4A_   (HID_ * E_ / 4)
#define NC4B_   (NREG_ * HID_ / 4)
#define NCAST_  ((NC4A_ + NC4B_ + 255) / 256)         // 3628
__global__ __launch_bounds__(256) void prep_kernel(
    const float* __restrict__ Wo, const float* __restrict__ Wv,
    unsigned short* __restrict__ WoT, unsigned short* __restrict__ WvT,
    const float* __restrict__ W1, unsigned short* __restrict__ W1b,
    const float* __restrict__ W2, unsigned short* __restrict__ W2b,
    const float* __restrict__ bv, const float* __restrict__ bo, float* __restrict__ t1v,
    const float* __restrict__ enc_W, const int* __restrict__ starts,
    unsigned short* __restrict__ Wpk) {
  __shared__ float tile[64][65];
  int bid = blockIdx.x;
  if (bid < 2 * NTR_) {
    int z = bid / NTR_, rem = bid % NTR_;
    const float* in = z ? Wv : Wo;
    unsigned short* out = z ? WvT : WoT;
    int c0 = (rem % 52) * 64, r0 = (rem / 52) * 64;
    int t = threadIdx.x;
    int ci = t & 63, ri0 = t >> 6;
    for (int ri = ri0; ri < 64; ri += 4)
      tile[ri][ci] = in[(size_t)(r0 + ri) * E_ + c0 + ci];
    __syncthreads();
    int rj = t & 63, i0 = t >> 6;
    for (int i = i0; i < 64; i += 4)
      out[(size_t)(c0 + i) * E_ + r0 + rj] = f2bf_rne(tile[rj][i]);
  } else if (bid < 2 * NTR_ + NCAST_) {
    int i = (bid - 2 * NTR_) * 256 + threadIdx.x;
    const float* src; unsigned short* dst; int idx;
    if (i < NC4A_) { src = W1; dst = W1b; idx = i; }
    else if (i < NC4A_ + NC4B_) { src = W2; dst = W2b; idx = i - NC4A_; }
    else return;
    float4 v = ((const float4*)src)[idx];
    ushort4 o;
    o.x = f2bf_rne(v.x); o.y = f2bf_rne(v.y); o.z = f2bf_rne(v.z); o.w = f2bf_rne(v.w);
    ((ushort4*)dst)[idx] = o;
  } else if (bid < 2 * NTR_ + NCAST_ + E_ / 4) {
    rowdot_body(Wo, bv, bo, t1v, E_, E_, bid - 2 * NTR_ - NCAST_);
  } else {
    pack_w_body(enc_W, starts, Wpk, bid - 2 * NTR_ - NCAST_ - E_ / 4);
  }
}

// ---------------- encoder body: shfl-free (no fused stats), zero LDS ----------------
__device__ __forceinline__ void encode_body(
    const float* __restrict__ x, const unsigned short* __restrict__ Wpk,
    const float* __restrict__ enc_b, const int* __restrict__ starts,
    const int* __restrict__ red_starts,
    unsigned short* __restrict__ yT, int r, int bg) {
  int tid = threadIdx.x;
  int wid = tid >> 6, lane = tid & 63;
  int lr = lane & 15, kg = lane >> 4;

  int size = 30 + (7 * r) % 90;
  int red  = (r == 332) ? 8 : (8 + r % 5);
  int st   = starts[r];
  int s8   = st & 7;
  int a0   = st & ~7;
  int rs   = red_starts[r];
  int nkc  = (s8 + size + 31) >> 5;
  int kmax = TOTAL_ - a0;

  bf16x8 wf[4];
  const unsigned short* wp = Wpk + (size_t)r * 2048 + lane * 8;
#pragma unroll
  for (int kc = 0; kc < 4; ++kc) wf[kc] = *(const bf16x8*)(wp + kc * 512);

  float bofs[4];
#pragma unroll
  for (int reg = 0; reg < 4; ++reg) {
    int oc = kg * 4 + reg;
    bofs[reg] = (oc < MAXO_) ? enc_b[r * MAXO_ + oc] : 0.f;
  }

  for (int t = 0; t < 4; ++t) {
    int b0 = bg * 256 + wid * 64 + t * 16;
    const float* xrow = x + (size_t)(b0 + lr) * TOTAL_ + a0;
    f32x4 acc = {0.f, 0.f, 0.f, 0.f};
#pragma unroll
    for (int kc = 0; kc < 4; ++kc) {
      if (kc < nkc) {
        int k0 = kc * 32 + kg * 8;
        if (k0 + 8 > kmax) k0 = kmax - 8;   // only all-zero-weight frags clamp
        float4 v0 = *(const float4*)(xrow + k0);
        float4 v1 = *(const float4*)(xrow + k0 + 4);
        bf16x8 xf;
        xf[0] = (short)f2bf_rne(v0.x); xf[1] = (short)f2bf_rne(v0.y);
        xf[2] = (short)f2bf_rne(v0.z); xf[3] = (short)f2bf_rne(v0.w);
        xf[4] = (short)f2bf_rne(v1.x); xf[5] = (short)f2bf_rne(v1.y);
        xf[6] = (short)f2bf_rne(v1.z); xf[7] = (short)f2bf_rne(v1.w);
        acc = __builtin_amdgcn_mfma_f32_16x16x32_bf16(wf[kc], xf, acc, 0, 0, 0);
      }
    }
    // C layout: col = lane&15 = batch, row = kg*4+reg = oc. Store only; stats later.
#pragma unroll
    for (int reg = 0; reg < 4; ++reg) {
      int oc = kg * 4 + reg;
      if (oc < red)
        yT[(size_t)(rs + oc) * B_ + b0 + lr] = f2bf_rne(acc[reg] + bofs[reg]);
    }
  }
}

// ---------------- GEMM body: 128x128 tile, BK=32, dbuf 2-phase, optional split-K ------
template <int KS, bool OUT_BF16>
__device__ __forceinline__ void gemm_body(
    const unsigned short* __restrict__ A, const unsigned short* __restrict__ W,
    float* __restrict__ Cf, unsigned short* __restrict__ Cb,
    int M, int N, int K, int bx, int by, int bz, unsigned short* smem) {
  unsigned short* a_lds = smem;
  unsigned short* b_lds = smem + 8192;
  int tid = threadIdx.x;
  int wid = tid >> 6, lane = tid & 63;
  int wr = wid >> 1, wc = wid & 1;
  int row0 = by * 128, col0 = bx * 128;
  int lr = lane & 15, kg = lane >> 4;
  int Klocal = K / KS;
  int kbase = bz * Klocal;

  int srow = tid >> 2, sk = (tid & 3) * 8;
  const unsigned short* aptr0 = A + (size_t)(row0 + srow) * K + kbase + sk;
  const unsigned short* aptr1 = aptr0 + (size_t)64 * K;
  int bcol0 = col0 + srow;      if (bcol0 > N - 1) bcol0 = N - 1;
  int bcol1 = col0 + 64 + srow; if (bcol1 > N - 1) bcol1 = N - 1;
  const unsigned short* bptr0 = W + (size_t)bcol0 * K + kbase + sk;
  const unsigned short* bptr1 = W + (size_t)bcol1 * K + kbase + sk;

  f32x4 acc[4][4] = {};
  int nk = Klocal >> 5;

#define STAGE_(buf, kc)                                                                             \
  do {                                                                                              \
    __builtin_amdgcn_global_load_lds((const __attribute__((address_space(1))) void*)(aptr0 + (kc)), \
        (__attribute__((address_space(3))) void*)(a_lds + (buf) * 4096 + wid * 512), 16, 0, 0);     \
    __builtin_amdgcn_global_load_lds((const __attribute__((address_space(1))) void*)(aptr1 + (kc)), \
        (__attribute__((address_space(3))) void*)(a_lds + (buf) * 4096 + 2048 + wid * 512), 16, 0, 0); \
    __builtin_amdgcn_global_load_lds((const __attribute__((address_space(1))) void*)(bptr0 + (kc)), \
        (__attribute__((address_space(3))) void*)(b_lds + (buf) * 4096 + wid * 512), 16, 0, 0);     \
    __builtin_amdgcn_global_load_lds((const __attribute__((address_space(1))) void*)(bptr1 + (kc)), \
        (__attribute__((address_space(3))) void*)(b_lds + (buf) * 4096 + 2048 + wid * 512), 16, 0, 0); \
  } while (0)

  STAGE_(0, 0);
  __syncthreads();
  int cur = 0;
  for (int t = 0; t < nk; ++t) {
    if (t + 1 < nk) STAGE_(cur ^ 1, (t + 1) * 32);
    bf16x8 a[4], b[4];
#pragma unroll
    for (int f = 0; f < 4; ++f) {
      a[f] = *(const bf16x8*)(a_lds + cur * 4096 + (wr * 64 + f * 16 + lr) * 32 + kg * 8);
      b[f] = *(const bf16x8*)(b_lds + cur * 4096 + (wc * 64 + f * 16 + lr) * 32 + kg * 8);
    }
#pragma unroll
    for (int i = 0; i < 4; ++i)
#pragma unroll
      for (int j = 0; j < 4; ++j)
        acc[i][j] = __builtin_amdgcn_mfma_f32_16x16x32_bf16(a[i], b[j], acc[i][j], 0, 0, 0);
    __syncthreads();
    cur ^= 1;
  }
#undef STAGE_

#pragma unroll
  for (int j = 0; j < 4; ++j) {
    int ccol = col0 + wc * 64 + j * 16 + lr;
    if (ccol >= N) continue;
#pragma unroll
    for (int i = 0; i < 4; ++i) {
#pragma unroll
      for (int reg = 0; reg < 4; ++reg) {
        int crow = row0 + wr * 64 + i * 16 + kg * 4 + reg;
        float v = acc[i][j][reg];
        if (KS == 1) {
          if (OUT_BF16) Cb[(size_t)crow * N + ccol] = f2bf_rne(v);
          else          Cf[(size_t)crow * N + ccol] = v;
        } else {
          Cf[((size_t)bz * M + crow) * N + ccol] = v;
        }
      }
    }
  }
}

// ---------------- K3 mega: Wa gemm (208) || encode (2664) || rowdot2 (256) ------------
#define WA_NB_  ((E_ / 128) * (HID_ / 128))   // 208
#define ENC_NB_ (R_ * 8)                       // 2664
__global__ __launch_bounds__(256) void mega_kernel(
    const float* __restrict__ x, const unsigned short* __restrict__ Wpk,
    const float* __restrict__ enc_b, const int* __restrict__ starts,
    const int* __restrict__ red_starts, unsigned short* __restrict__ yT,
    const unsigned short* __restrict__ W1b, const unsigned short* __restrict__ WoT,
    unsigned short* __restrict__ Wa_bf,
    const float* __restrict__ W1, const float* __restrict__ t1v,
    const float* __restrict__ b1, float* __restrict__ zbv) {
  __shared__ __align__(16) unsigned short smem[16384];
  int bid = blockIdx.x;
  if (bid < WA_NB_) {
    gemm_body<1, true>(W1b, WoT, nullptr, Wa_bf, HID_, E_, E_,
                       bid % (E_ / 128), bid / (E_ / 128), 0, smem);
  } else if (bid < WA_NB_ + ENC_NB_) {
    int eb = bid - WA_NB_;
    encode_body(x, Wpk, enc_b, starts, red_starts, yT, eb >> 3, eb & 7);
  } else {
    rowdot_body(W1, t1v, b1, zbv, HID_, E_, bid - WA_NB_ - ENC_NB_);
  }
}

// ---------------- K4: Wb gemm (KS=2, 416) || bn1_stats from yT (208) ----------------
#define WB2_NB_ (WA_NB_ * 2)                  // 416
#define ST_NB_  ((CONCAT_ + 15) / 16)         // 208
__global__ __launch_bounds__(256) void wb_stats_kernel(
    const unsigned short* __restrict__ Wa_bf, const unsigned short* __restrict__ WvT,
    float* __restrict__ Cpart,
    const unsigned short* __restrict__ yT, float* __restrict__ mean, float* __restrict__ rstd) {
  __shared__ __align__(16) unsigned short smem[16384];
  int bid = blockIdx.x;
  if (bid < WB2_NB_) {
    int z = bid / WA_NB_, rem = bid % WA_NB_;
    gemm_body<2, false>(Wa_bf, WvT, Cpart, nullptr, HID_, E_, E_,
                        rem % (E_ / 128), rem / (E_ / 128), z, smem);
  } else {
    // 16 features per block; 16 lanes per feature read 128 bf16 each (coalesced rows)
    int tb = bid - WB2_NB_;
    int t = threadIdx.x;
    int f = tb * 16 + (t >> 4);
    int j = t & 15;
    if (f >= CONCAT_) return;
    const unsigned short* p = yT + (size_t)f * B_ + j * 128;
    float s = 0.f, s2 = 0.f;
#pragma unroll
    for (int i = 0; i < 16; ++i) {
      bf16x8 v = *(const bf16x8*)(p + i * 8);
#pragma unroll
      for (int e = 0; e < 8; ++e) {
        float xv = bf2f((unsigned short)v[e]);
        s += xv; s2 = fmaf(xv, xv, s2);
      }
    }
#pragma unroll
    for (int m = 1; m <= 8; m <<= 1) { s += __shfl_xor(s, m); s2 += __shfl_xor(s2, m); }
    if (j == 0) {
      float mm = s / B_;
      float var = s2 / B_ - mm * mm;
      mean[f] = mm;
      rstd[f] = rsqrtf(var + EPS_);
    }
  }
}

// ---------------- K5: bn1_transpose+pad (1664) || combine Wb (3328) ----------------
#define TR_NB_ ((E_ / 64) * (B_ / 64))        // 1664
#define CWB_NB_ (HID_ * E_ / 4 / 256)         // 3328
__global__ __launch_bounds__(256) void trans_comb_kernel(
    const unsigned short* __restrict__ yT, const float* __restrict__ mean,
    const float* __restrict__ rstd, const float* __restrict__ g,
    const float* __restrict__ bb, unsigned short* __restrict__ Y,
    const float* __restrict__ Cpart, unsigned short* __restrict__ Wb_bf) {
  __shared__ float tile[64][65];
  int bid = blockIdx.x;
  if (bid < TR_NB_) {
    int cc0 = (bid % 52) * 64, b0 = (bid / 52) * 64;
    int t = threadIdx.x;
    int bi = t & 63, ci0 = t >> 6;
    for (int ci = ci0; ci < 64; ci += 4) {
      int c = cc0 + ci - 1;              // F.pad(1,2): output col cc -> feature cc-1
      float v = 0.f;
      if (c >= 0 && c < CONCAT_) {
        float f = bf2f(yT[(size_t)c * B_ + b0 + bi]);
        v = (f - mean[c]) * rstd[c] * g[c] + bb[c];
        v = v > 0.f ? v : 0.3f * v;
      }
      tile[ci][bi] = v;
    }
    __syncthreads();
    int cj = t & 63, bj0 = t >> 6;
    for (int bj = bj0; bj < 64; bj += 4)
      Y[(size_t)(b0 + bj) * E_ + cc0 + cj] = f2bf_rne(tile[cj][bj]);
  } else {
    int i4 = (bid - TR_NB_) * 256 + threadIdx.x;   // float4 index, < HID_*E_/4
    const int MN4 = HID_ * E_ / 4;
    if (i4 >= MN4) return;
    float4 a = ((const float4*)Cpart)[i4];
    float4 b = ((const float4*)(Cpart + (size_t)HID_ * E_))[i4];
    ushort4 o;
    o.x = f2bf_rne(a.x + b.x); o.y = f2bf_rne(a.y + b.y);
    o.z = f2bf_rne(a.z + b.z); o.w = f2bf_rne(a.w + b.w);
    ((ushort4*)Wb_bf)[i4] = o;
  }
}

// ---------------- standalone GEMM wrapper ----------------
template <int KS, bool OUT_BF16>
__global__ __launch_bounds__(256) void gemm_kernel(
    const unsigned short* __restrict__ A, const unsigned short* __restrict__ W,
    float* __restrict__ Cf, unsigned short* __restrict__ Cb, int M, int N, int K) {
  __shared__ __align__(16) unsigned short smem[16384];
  gemm_body<KS, OUT_BF16>(A, W, Cf, Cb, M, N, K, blockIdx.x, blockIdx.y, blockIdx.z, smem);
}

// ---------------- fused: Z combine (4 slices + zb) + BN2 partial stats ----------------
__global__ __launch_bounds__(256) void combZ_stats_kernel(
    const float* __restrict__ Cpart, const float* __restrict__ zb,
    float* __restrict__ Z, float* __restrict__ pS, float* __restrict__ pS2) {
  int c = blockIdx.x * 256 + threadIdx.x;
  int ry = blockIdx.y;
  float zbc = zb[c];
  float s1 = 0.f, s2 = 0.f;
  for (int r = ry * 16; r < ry * 16 + 16; ++r) {
    float v = zbc;
#pragma unroll
    for (int z = 0; z < 4; ++z) v += Cpart[((size_t)z * B_ + r) * HID_ + c];
    Z[(size_t)r * HID_ + c] = v;
    s1 += v; s2 = fmaf(v, v, s2);
  }
  pS[ry * HID_ + c] = s1;
  pS2[ry * HID_ + c] = s2;
}

__global__ __launch_bounds__(256) void colstats_final_kernel(
    const float* __restrict__ pS, const float* __restrict__ pS2,
    float* __restrict__ mean, float* __restrict__ rstd) {
  int c = blockIdx.x * 256 + threadIdx.x;
  if (c >= HID_) return;
  float s = 0.f, s2 = 0.f;
  for (int i = 0; i < NS2_; ++i) { s += pS[i * HID_ + c]; s2 += pS2[i * HID_ + c]; }
  float m = s / B_;
  float v = s2 / B_ - m * m;
  mean[c] = m;
  rstd[c] = rsqrtf(v + EPS_);
}

// ---------------- BN2 apply + LeakyReLU(0.1) -> bf16 ----------------
__global__ __launch_bounds__(256) void bn2_apply_kernel(
    const float* __restrict__ Z, const float* __restrict__ mean, const float* __restrict__ rstd,
    const float* __restrict__ g, const float* __restrict__ bb, unsigned short* __restrict__ R) {
  int i = blockIdx.x * 256 + threadIdx.x;
  int c = i & (HID_ - 1);
  float v = (Z[i] - mean[c]) * rstd[c] * g[c] + bb[c];
  v = v > 0.f ? v : 0.1f * v;
  R[i] = f2bf_rne(v);
}

// ---------------- classifier with fused W2 split-K combine ----------------
__global__ __launch_bounds__(256) void classifier_kernel(
    const float* __restrict__ Cpart, const float* __restrict__ b2,
    const float* __restrict__ Wc, const float* __restrict__ bc,
    float* __restrict__ reg_out, float* __restrict__ ypred) {
  int b = blockIdx.x;
  __shared__ __align__(16) float rrow[NREG_];
  __shared__ float sl[256];
  int tid = threadIdx.x;
  for (int i = tid; i < NREG_; i += 256) {
    float s = b2[i];
#pragma unroll
    for (int z = 0; z < 4; ++z) s += Cpart[((size_t)z * B_ + b) * NREG_ + i];
    rrow[i] = s;
    reg_out[(size_t)b * NREG_ + i] = s;
  }
  __syncthreads();
  float s = -1e30f;
  if (tid < NCLS_) {
    const float* w = Wc + (size_t)tid * NREG_;
    float acc = 0.f;
    for (int k = 0; k < NREG_; k += 4) {
      float4 wv = *(const float4*)(w + k);
      float4 rv = *(const float4*)(&rrow[k]);
      acc = fmaf(wv.x, rv.x, acc); acc = fmaf(wv.y, rv.y, acc);
      acc = fmaf(wv.z, rv.z, acc); acc = fmaf(wv.w, rv.w, acc);
    }
    s = acc + bc[tid];
  }
  sl[tid] = s;
  __syncthreads();
  for (int o = 128; o > 0; o >>= 1) {
    if (tid < o) sl[tid] = fmaxf(sl[tid], sl[tid + o]);
    __syncthreads();
  }
  float mx = sl[0];
  __syncthreads();
  float e = (tid < NCLS_) ? __expf(s - mx) : 0.f;
  sl[tid] = e;
  __syncthreads();
  for (int o = 128; o > 0; o >>= 1) {
    if (tid < o) sl[tid] += sl[tid + o];
    __syncthreads();
  }
  if (tid < NCLS_) ypred[(size_t)b * NCLS_ + tid] = e / sl[0];
}

// ---------------- host orchestration ----------------
extern "C" void kernel_launch(void* const* d_in, const int* in_sizes, int n_in,
                              void* d_out, int out_size, void* d_ws, size_t ws_size,
                              hipStream_t stream) {
  const float* x     = (const float*)d_in[0];
  const float* enc_W = (const float*)d_in[1];
  const float* enc_b = (const float*)d_in[2];
  const float* bn1_g = (const float*)d_in[3];
  const float* bn1_b = (const float*)d_in[4];
  const float* Wqkv  = (const float*)d_in[5];
  const float* bqkv  = (const float*)d_in[6];
  const float* Wo    = (const float*)d_in[7];
  const float* bo    = (const float*)d_in[8];
  const float* W1    = (const float*)d_in[9];
  const float* b1    = (const float*)d_in[10];
  const float* bn2_g = (const float*)d_in[11];
  const float* bn2_b = (const float*)d_in[12];
  const float* W2    = (const float*)d_in[13];
  const float* b2    = (const float*)d_in[14];
  const float* Wc    = (const float*)d_in[15];
  const float* bc    = (const float*)d_in[16];

  char* ws = (char*)d_ws;
  size_t off = 0;
  auto alloc = [&](size_t bytes) -> void* {
    void* p = ws + off;
    off += (bytes + 255) & ~(size_t)255;
    return p;
  };

  unsigned short* yT     = (unsigned short*)alloc((size_t)CONCAT_ * B_ * 2); // bf16; reused for Z(f32)
  float*          mean1  = (float*)alloc(CONCAT_ * 4);
  float*          rstd1  = (float*)alloc(CONCAT_ * 4);
  unsigned short* Ybf    = (unsigned short*)alloc((size_t)B_ * E_ * 2);
  unsigned short* Rbf    = (unsigned short*)alloc((size_t)B_ * HID_ * 2);
  unsigned short* WoT_bf = (unsigned short*)alloc((size_t)E_ * E_ * 2);
  unsigned short* WvT_bf = (unsigned short*)alloc((size_t)E_ * E_ * 2);
  unsigned short* W1_bf  = (unsigned short*)alloc((size_t)HID_ * E_ * 2);
  unsigned short* W2_bf  = (unsigned short*)alloc((size_t)NREG_ * HID_ * 2);
  unsigned short* Wa_bf  = (unsigned short*)alloc((size_t)HID_ * E_ * 2);
  unsigned short* Wb_bf  = (unsigned short*)alloc((size_t)HID_ * E_ * 2);
  unsigned short* Wpk    = (unsigned short*)alloc((size_t)R_ * 2048 * 2);
  float*          Cpart  = (float*)alloc((size_t)4 * B_ * HID_ * 4);
  float*          t1v    = (float*)alloc(E_ * 4);
  float*          zbv    = (float*)alloc(HID_ * 4);
  float*          partS  = (float*)alloc((size_t)NS2_ * HID_ * 4);
  float*          partS2 = (float*)alloc((size_t)NS2_ * HID_ * 4);
  float*          mean2  = (float*)alloc(HID_ * 4);
  float*          rstd2  = (float*)alloc(HID_ * 4);
  int*            starts = (int*)alloc(R_ * 4);
  int*            redst  = (int*)alloc(R_ * 4);

  float* Z = (float*)yT;   // yT dead after trans_comb

  // K1: layout
  layout_kernel<<<1, 1, 0, stream>>>(starts, redst);
  // K2: prep — transposes || casts || rowdot1 || pack_w
  prep_kernel<<<2 * NTR_ + NCAST_ + E_ / 4 + R_, 256, 0, stream>>>(
      Wo, Wqkv + (size_t)2 * E_ * E_, WoT_bf, WvT_bf,
      W1, W1_bf, W2, W2_bf, bqkv + 2 * E_, bo, t1v, enc_W, starts, Wpk);
  // K3 mega: Wa gemm || encode (shfl-free) || rowdot2
  mega_kernel<<<WA_NB_ + ENC_NB_ + HID_ / 4, 256, 0, stream>>>(
      x, Wpk, enc_b, starts, redst, yT, W1_bf, WoT_bf, Wa_bf, W1, t1v, b1, zbv);
  // K4: Wb gemm (KS2) || bn1_stats from yT
  wb_stats_kernel<<<WB2_NB_ + ST_NB_, 256, 0, stream>>>(
      Wa_bf, WvT_bf, Cpart, yT, mean1, rstd1);
  // K5: bn1 transpose+pad || combine Wb -> bf16
  trans_comb_kernel<<<TR_NB_ + CWB_NB_, 256, 0, stream>>>(
      yT, mean1, rstd1, bn1_g, bn1_b, Ybf, Cpart, Wb_bf);
  // K6: Z = Y @ Wb^T (KS=4)
  gemm_kernel<4, false><<<dim3(HID_ / 128, B_ / 128, 4), 256, 0, stream>>>(
      Ybf, Wb_bf, Cpart, nullptr, B_, HID_, E_);
  // K7: Z combine + zb + BN2 partial stats
  combZ_stats_kernel<<<dim3(HID_ / 256, NS2_), 256, 0, stream>>>(Cpart, zbv, Z, partS, partS2);
  // K8: BN2 stats finalize
  colstats_final_kernel<<<(HID_ + 255) / 256, 256, 0, stream>>>(partS, partS2, mean2, rstd2);
  // K9: BN2 apply -> bf16
  bn2_apply_kernel<<<(B_ * HID_) / 256, 256, 0, stream>>>(Z, mean2, rstd2, bn2_g, bn2_b, Rbf);
  // K10: reg partials: R @ W2^T (KS=4)
  gemm_kernel<4, false><<<dim3((NREG_ + 127) / 128, B_ / 128, 4), 256, 0, stream>>>(
      Rbf, W2_bf, Cpart, nullptr, B_, NREG_, HID_);
  // K11: classifier (fused W2 combine) -> reg_out, y_pred
  float* reg_out = (float*)d_out;
  classifier_kernel<<<B_, 256, 0, stream>>>(
      Cpart, b2, Wc, bc, reg_out, reg_out + (size_t)B_ * NREG_);
}

// Round 13
// 309.669 us; speedup vs baseline: 1.1336x; 1.0128x over previous
//
#include <hip/hip_runtime.h>
#include <hip/hip_bf16.h>

#define B_      2048
#define R_      333
#define MAXI_   119
#define MAXO_   12
#define CONCAT_ 3325
#define E_      3328
#define TOTAL_  24696
#define HID_    1024
#define NREG_   300
#define NCLS_   180
#define EPS_    1e-5f
#define NS2_    128

typedef __attribute__((ext_vector_type(8))) short bf16x8;
typedef __attribute__((ext_vector_type(4))) float f32x4;

static __device__ inline unsigned short f2bf_rne(float f) {
  unsigned u;
  __builtin_memcpy(&u, &f, 4);
  u += 0x7fff + ((u >> 16) & 1);
  return (unsigned short)(u >> 16);
}
static __device__ inline float bf2f(unsigned short s) {
  unsigned u = (unsigned)s << 16;
  float f;
  __builtin_memcpy(&f, &u, 4);
  return f;
}

// ---------------- layout ----------------
__global__ void layout_kernel(int* __restrict__ starts, int* __restrict__ red_starts) {
  if (threadIdx.x == 0 && blockIdx.x == 0) {
    int s = 0, rs = 0;
    for (int r = 0; r < R_; ++r) {
      starts[r] = s;
      red_starts[r] = rs;
      s += 30 + (7 * r) % 90;
      rs += (r == 332) ? 8 : (8 + r % 5);
    }
  }
}

// ---------------- rowdot body ----------------
__device__ __forceinline__ void rowdot_body(
    const float* __restrict__ A, const float* __restrict__ v, const float* __restrict__ b,
    float* __restrict__ out, int N, int K, int jb) {
  int wid = threadIdx.x >> 6, lane = threadIdx.x & 63;
  int j = jb * 4 + wid;
  if (j >= N) return;
  const float* row = A + (size_t)j * K;
  float s = 0.f;
  for (int k = lane; k < K; k += 64) s = fmaf(row[k], v[k], s);
  for (int o = 32; o; o >>= 1) s += __shfl_down(s, o);
  if (lane == 0) out[j] = s + b[j];
}

// ---------------- pack enc_W body ----------------
__device__ __forceinline__ void pack_w_body(const float* __restrict__ enc_W,
                                            const int* __restrict__ starts,
                                            unsigned short* __restrict__ Wpk, int r) {
  int tid = threadIdx.x;
  int kc = tid >> 6, lane = tid & 63;
  int size = 30 + (7 * r) % 90;
  int s8 = starts[r] & 7;
  int oc = lane & 15;
  int k0 = kc * 32 + (lane >> 4) * 8;
  unsigned short o[8];
#pragma unroll
  for (int e = 0; e < 8; ++e) {
    int k = k0 + e - s8;
    float v = 0.f;
    if (oc < MAXO_ && k >= 0 && k < size) v = enc_W[((size_t)r * MAXO_ + oc) * MAXI_ + k];
    o[e] = f2bf_rne(v);
  }
  unsigned short* dst = Wpk + ((size_t)r * 4 + kc) * 512 + lane * 8;
  *(ushort4*)dst = *(ushort4*)&o[0];
  *(ushort4*)(dst + 4) = *(ushort4*)&o[4];
}

// ---------------- K2 prep: transposes(Wo,Wv) || casts(W1,W2) || rowdot1 || pack_w -----
#define NTR_    ((E_ / 64) * (E_ / 64))               // 2704 per matrix
#define NC4A_   (HID_ * E_ / 4)
#define NC4B_   (NREG_ * HID_ / 4)
#define NCAST_  ((NC4A_ + NC4B_ + 255) / 256)         // 3628
__global__ __launch_bounds__(256) void prep_kernel(
    const float* __restrict__ Wo, const float* __restrict__ Wv,
    unsigned short* __restrict__ WoT, unsigned short* __restrict__ WvT,
    const float* __restrict__ W1, unsigned short* __restrict__ W1b,
    const float* __restrict__ W2, unsigned short* __restrict__ W2b,
    const float* __restrict__ bv, const float* __restrict__ bo, float* __restrict__ t1v,
    const float* __restrict__ enc_W, const int* __restrict__ starts,
    unsigned short* __restrict__ Wpk) {
  __shared__ float tile[64][65];
  int bid = blockIdx.x;
  if (bid < 2 * NTR_) {
    int z = bid / NTR_, rem = bid % NTR_;
    const float* in = z ? Wv : Wo;
    unsigned short* out = z ? WvT : WoT;
    int c0 = (rem % 52) * 64, r0 = (rem / 52) * 64;
    int t = threadIdx.x;
    int ci = t & 63, ri0 = t >> 6;
    for (int ri = ri0; ri < 64; ri += 4)
      tile[ri][ci] = in[(size_t)(r0 + ri) * E_ + c0 + ci];
    __syncthreads();
    int rj = t & 63, i0 = t >> 6;
    for (int i = i0; i < 64; i += 4)
      out[(size_t)(c0 + i) * E_ + r0 + rj] = f2bf_rne(tile[rj][i]);
  } else if (bid < 2 * NTR_ + NCAST_) {
    int i = (bid - 2 * NTR_) * 256 + threadIdx.x;
    const float* src; unsigned short* dst; int idx;
    if (i < NC4A_) { src = W1; dst = W1b; idx = i; }
    else if (i < NC4A_ + NC4B_) { src = W2; dst = W2b; idx = i - NC4A_; }
    else return;
    float4 v = ((const float4*)src)[idx];
    ushort4 o;
    o.x = f2bf_rne(v.x); o.y = f2bf_rne(v.y); o.z = f2bf_rne(v.z); o.w = f2bf_rne(v.w);
    ((ushort4*)dst)[idx] = o;
  } else if (bid < 2 * NTR_ + NCAST_ + E_ / 4) {
    rowdot_body(Wo, bv, bo, t1v, E_, E_, bid - 2 * NTR_ - NCAST_);
  } else {
    pack_w_body(enc_W, starts, Wpk, bid - 2 * NTR_ - NCAST_ - E_ / 4);
  }
}

// ---------------- encoder body: 1 tile (16 rows) per wave, zero LDS ----------------
__device__ __forceinline__ void encode_body(
    const float* __restrict__ x, const unsigned short* __restrict__ Wpk,
    const float* __restrict__ enc_b, const int* __restrict__ starts,
    const int* __restrict__ red_starts,
    unsigned short* __restrict__ yT, int r, int bg) {
  int tid = threadIdx.x;
  int wid = tid >> 6, lane = tid & 63;
  int lr = lane & 15, kg = lane >> 4;

  int size = 30 + (7 * r) % 90;
  int red  = (r == 332) ? 8 : (8 + r % 5);
  int st   = starts[r];
  int s8   = st & 7;
  int a0   = st & ~7;
  int rs   = red_starts[r];
  int nkc  = (s8 + size + 31) >> 5;
  int kmax = TOTAL_ - a0;

  bf16x8 wf[4];
  const unsigned short* wp = Wpk + (size_t)r * 2048 + lane * 8;
#pragma unroll
  for (int kc = 0; kc < 4; ++kc) wf[kc] = *(const bf16x8*)(wp + kc * 512);

  float bofs[4];
#pragma unroll
  for (int reg = 0; reg < 4; ++reg) {
    int oc = kg * 4 + reg;
    bofs[reg] = (oc < MAXO_) ? enc_b[r * MAXO_ + oc] : 0.f;
  }

  int b0 = bg * 64 + wid * 16;
  const float* xrow = x + (size_t)(b0 + lr) * TOTAL_ + a0;
  f32x4 acc = {0.f, 0.f, 0.f, 0.f};
#pragma unroll
  for (int kc = 0; kc < 4; ++kc) {
    if (kc < nkc) {
      int k0 = kc * 32 + kg * 8;
      if (k0 + 8 > kmax) k0 = kmax - 8;   // only all-zero-weight frags clamp
      float4 v0 = *(const float4*)(xrow + k0);
      float4 v1 = *(const float4*)(xrow + k0 + 4);
      bf16x8 xf;
      xf[0] = (short)f2bf_rne(v0.x); xf[1] = (short)f2bf_rne(v0.y);
      xf[2] = (short)f2bf_rne(v0.z); xf[3] = (short)f2bf_rne(v0.w);
      xf[4] = (short)f2bf_rne(v1.x); xf[5] = (short)f2bf_rne(v1.y);
      xf[6] = (short)f2bf_rne(v1.z); xf[7] = (short)f2bf_rne(v1.w);
      acc = __builtin_amdgcn_mfma_f32_16x16x32_bf16(wf[kc], xf, acc, 0, 0, 0);
    }
  }
  // C layout: col = lane&15 = batch, row = kg*4+reg = oc
#pragma unroll
  for (int reg = 0; reg < 4; ++reg) {
    int oc = kg * 4 + reg;
    if (oc < red)
      yT[(size_t)(rs + oc) * B_ + b0 + lr] = f2bf_rne(acc[reg] + bofs[reg]);
  }
}

// ---------------- GEMM body: 128x128 tile, BK=32, dbuf 2-phase, optional split-K ------
template <int KS, bool OUT_BF16>
__device__ __forceinline__ void gemm_body(
    const unsigned short* __restrict__ A, const unsigned short* __restrict__ W,
    float* __restrict__ Cf, unsigned short* __restrict__ Cb,
    int M, int N, int K, int bx, int by, int bz, unsigned short* smem) {
  unsigned short* a_lds = smem;
  unsigned short* b_lds = smem + 8192;
  int tid = threadIdx.x;
  int wid = tid >> 6, lane = tid & 63;
  int wr = wid >> 1, wc = wid & 1;
  int row0 = by * 128, col0 = bx * 128;
  int lr = lane & 15, kg = lane >> 4;
  int Klocal = K / KS;
  int kbase = bz * Klocal;

  int srow = tid >> 2, sk = (tid & 3) * 8;
  const unsigned short* aptr0 = A + (size_t)(row0 + srow) * K + kbase + sk;
  const unsigned short* aptr1 = aptr0 + (size_t)64 * K;
  int bcol0 = col0 + srow;      if (bcol0 > N - 1) bcol0 = N - 1;
  int bcol1 = col0 + 64 + srow; if (bcol1 > N - 1) bcol1 = N - 1;
  const unsigned short* bptr0 = W + (size_t)bcol0 * K + kbase + sk;
  const unsigned short* bptr1 = W + (size_t)bcol1 * K + kbase + sk;

  f32x4 acc[4][4] = {};
  int nk = Klocal >> 5;

#define STAGE_(buf, kc)                                                                             \
  do {                                                                                              \
    __builtin_amdgcn_global_load_lds((const __attribute__((address_space(1))) void*)(aptr0 + (kc)), \
        (__attribute__((address_space(3))) void*)(a_lds + (buf) * 4096 + wid * 512), 16, 0, 0);     \
    __builtin_amdgcn_global_load_lds((const __attribute__((address_space(1))) void*)(aptr1 + (kc)), \
        (__attribute__((address_space(3))) void*)(a_lds + (buf) * 4096 + 2048 + wid * 512), 16, 0, 0); \
    __builtin_amdgcn_global_load_lds((const __attribute__((address_space(1))) void*)(bptr0 + (kc)), \
        (__attribute__((address_space(3))) void*)(b_lds + (buf) * 4096 + wid * 512), 16, 0, 0);     \
    __builtin_amdgcn_global_load_lds((const __attribute__((address_space(1))) void*)(bptr1 + (kc)), \
        (__attribute__((address_space(3))) void*)(b_lds + (buf) * 4096 + 2048 + wid * 512), 16, 0, 0); \
  } while (0)

  STAGE_(0, 0);
  __syncthreads();
  int cur = 0;
  for (int t = 0; t < nk; ++t) {
    if (t + 1 < nk) STAGE_(cur ^ 1, (t + 1) * 32);
    bf16x8 a[4], b[4];
#pragma unroll
    for (int f = 0; f < 4; ++f) {
      a[f] = *(const bf16x8*)(a_lds + cur * 4096 + (wr * 64 + f * 16 + lr) * 32 + kg * 8);
      b[f] = *(const bf16x8*)(b_lds + cur * 4096 + (wc * 64 + f * 16 + lr) * 32 + kg * 8);
    }
#pragma unroll
    for (int i = 0; i < 4; ++i)
#pragma unroll
      for (int j = 0; j < 4; ++j)
        acc[i][j] = __builtin_amdgcn_mfma_f32_16x16x32_bf16(a[i], b[j], acc[i][j], 0, 0, 0);
    __syncthreads();
    cur ^= 1;
  }
#undef STAGE_

#pragma unroll
  for (int j = 0; j < 4; ++j) {
    int ccol = col0 + wc * 64 + j * 16 + lr;
    if (ccol >= N) continue;
#pragma unroll
    for (int i = 0; i < 4; ++i) {
#pragma unroll
      for (int reg = 0; reg < 4; ++reg) {
        int crow = row0 + wr * 64 + i * 16 + kg * 4 + reg;
        float v = acc[i][j][reg];
        if (KS == 1) {
          if (OUT_BF16) Cb[(size_t)crow * N + ccol] = f2bf_rne(v);
          else          Cf[(size_t)crow * N + ccol] = v;
        } else {
          Cf[((size_t)bz * M + crow) * N + ccol] = v;
        }
      }
    }
  }
}

// ---------------- K3: Wa gemm (208) || encode rows 0..1023 (5328) || rowdot2 ----------
#define WA_NB_   ((E_ / 128) * (HID_ / 128))   // 208
#define ENCH_NB_ (R_ * 16)                      // 5328 (half of batch, 1 tile/wave)
__global__ __launch_bounds__(256) void mega_a_kernel(
    const float* __restrict__ x, const unsigned short* __restrict__ Wpk,
    const float* __restrict__ enc_b, const int* __restrict__ starts,
    const int* __restrict__ red_starts, unsigned short* __restrict__ yT,
    const unsigned short* __restrict__ W1b, const unsigned short* __restrict__ WoT,
    unsigned short* __restrict__ Wa_bf,
    const float* __restrict__ W1, const float* __restrict__ t1v,
    const float* __restrict__ b1, float* __restrict__ zbv) {
  __shared__ __align__(16) unsigned short smem[16384];
  int bid = blockIdx.x;
  if (bid < WA_NB_) {
    gemm_body<1, true>(W1b, WoT, nullptr, Wa_bf, HID_, E_, E_,
                       bid % (E_ / 128), bid / (E_ / 128), 0, smem);
  } else if (bid < WA_NB_ + ENCH_NB_) {
    int eb = bid - WA_NB_;
    encode_body(x, Wpk, enc_b, starts, red_starts, yT, eb >> 4, eb & 15);
  } else {
    rowdot_body(W1, t1v, b1, zbv, HID_, E_, bid - WA_NB_ - ENCH_NB_);
  }
}

// ---------------- K4: Wb gemm (KS=2, 416) || encode rows 1024..2047 (5328) ------------
#define WB2_NB_ (WA_NB_ * 2)                   // 416
__global__ __launch_bounds__(256) void mega_b_kernel(
    const float* __restrict__ x, const unsigned short* __restrict__ Wpk,
    const float* __restrict__ enc_b, const int* __restrict__ starts,
    const int* __restrict__ red_starts, unsigned short* __restrict__ yT,
    const unsigned short* __restrict__ Wa_bf, const unsigned short* __restrict__ WvT,
    float* __restrict__ Cpart) {
  __shared__ __align__(16) unsigned short smem[16384];
  int bid = blockIdx.x;
  if (bid < WB2_NB_) {
    int z = bid / WA_NB_, rem = bid % WA_NB_;
    gemm_body<2, false>(Wa_bf, WvT, Cpart, nullptr, HID_, E_, E_,
                        rem % (E_ / 128), rem / (E_ / 128), z, smem);
  } else {
    int eb = bid - WB2_NB_;
    encode_body(x, Wpk, enc_b, starts, red_starts, yT, eb >> 4, 16 + (eb & 15));
  }
}

// ---------------- K5: bn1_stats from yT (208) || combine Wb -> bf16 (3328) ------------
#define ST_NB_  ((CONCAT_ + 15) / 16)          // 208
#define CWB_NB_ (HID_ * E_ / 4 / 256)          // 3328
__global__ __launch_bounds__(256) void stats_comb_kernel(
    const unsigned short* __restrict__ yT, float* __restrict__ mean, float* __restrict__ rstd,
    const float* __restrict__ Cpart, unsigned short* __restrict__ Wb_bf) {
  int bid = blockIdx.x;
  if (bid < ST_NB_) {
    // 16 features per block; 16 lanes per feature read 128 bf16 each (coalesced rows)
    int t = threadIdx.x;
    int f = bid * 16 + (t >> 4);
    int j = t & 15;
    if (f >= CONCAT_) return;
    const unsigned short* p = yT + (size_t)f * B_ + j * 128;
    float s = 0.f, s2 = 0.f;
#pragma unroll
    for (int i = 0; i < 16; ++i) {
      bf16x8 v = *(const bf16x8*)(p + i * 8);
#pragma unroll
      for (int e = 0; e < 8; ++e) {
        float xv = bf2f((unsigned short)v[e]);
        s += xv; s2 = fmaf(xv, xv, s2);
      }
    }
#pragma unroll
    for (int m = 1; m <= 8; m <<= 1) { s += __shfl_xor(s, m); s2 += __shfl_xor(s2, m); }
    if (j == 0) {
      float mm = s / B_;
      float var = s2 / B_ - mm * mm;
      mean[f] = mm;
      rstd[f] = rsqrtf(var + EPS_);
    }
  } else {
    int i4 = (bid - ST_NB_) * 256 + threadIdx.x;
    const int MN4 = HID_ * E_ / 4;
    if (i4 >= MN4) return;
    float4 a = ((const float4*)Cpart)[i4];
    float4 b = ((const float4*)(Cpart + (size_t)HID_ * E_))[i4];
    ushort4 o;
    o.x = f2bf_rne(a.x + b.x); o.y = f2bf_rne(a.y + b.y);
    o.z = f2bf_rne(a.z + b.z); o.w = f2bf_rne(a.w + b.w);
    ((ushort4*)Wb_bf)[i4] = o;
  }
}

// ---------------- K6: bn1 apply + transpose + pad (bf16 in/out) ----------------
#define TR_NB_ ((E_ / 64) * (B_ / 64))         // 1664
__global__ __launch_bounds__(256) void bn1_transpose_kernel(
    const unsigned short* __restrict__ yT, const float* __restrict__ mean,
    const float* __restrict__ rstd, const float* __restrict__ g,
    const float* __restrict__ bb, unsigned short* __restrict__ Y) {
  __shared__ float tile[64][65];
  int bid = blockIdx.x;
  int cc0 = (bid % 52) * 64, b0 = (bid / 52) * 64;
  int t = threadIdx.x;
  int bi = t & 63, ci0 = t >> 6;
  for (int ci = ci0; ci < 64; ci += 4) {
    int c = cc0 + ci - 1;              // F.pad(1,2): output col cc -> feature cc-1
    float v = 0.f;
    if (c >= 0 && c < CONCAT_) {
      float f = bf2f(yT[(size_t)c * B_ + b0 + bi]);
      v = (f - mean[c]) * rstd[c] * g[c] + bb[c];
      v = v > 0.f ? v : 0.3f * v;
    }
    tile[ci][bi] = v;
  }
  __syncthreads();
  int cj = t & 63, bj0 = t >> 6;
  for (int bj = bj0; bj < 64; bj += 4)
    Y[(size_t)(b0 + bj) * E_ + cc0 + cj] = f2bf_rne(tile[cj][bj]);
}

// ---------------- standalone GEMM wrapper ----------------
template <int KS, bool OUT_BF16>
__global__ __launch_bounds__(256) void gemm_kernel(
    const unsigned short* __restrict__ A, const unsigned short* __restrict__ W,
    float* __restrict__ Cf, unsigned short* __restrict__ Cb, int M, int N, int K) {
  __shared__ __align__(16) unsigned short smem[16384];
  gemm_body<KS, OUT_BF16>(A, W, Cf, Cb, M, N, K, blockIdx.x, blockIdx.y, blockIdx.z, smem);
}

// ---------------- fused: Z combine (4 slices + zb) + BN2 partial stats ----------------
__global__ __launch_bounds__(256) void combZ_stats_kernel(
    const float* __restrict__ Cpart, const float* __restrict__ zb,
    float* __restrict__ Z, float* __restrict__ pS, float* __restrict__ pS2) {
  int c = blockIdx.x * 256 + threadIdx.x;
  int ry = blockIdx.y;
  float zbc = zb[c];
  float s1 = 0.f, s2 = 0.f;
  for (int r = ry * 16; r < ry * 16 + 16; ++r) {
    float v = zbc;
#pragma unroll
    for (int z = 0; z < 4; ++z) v += Cpart[((size_t)z * B_ + r) * HID_ + c];
    Z[(size_t)r * HID_ + c] = v;
    s1 += v; s2 = fmaf(v, v, s2);
  }
  pS[ry * HID_ + c] = s1;
  pS2[ry * HID_ + c] = s2;
}

__global__ __launch_bounds__(256) void colstats_final_kernel(
    const float* __restrict__ pS, const float* __restrict__ pS2,
    float* __restrict__ mean, float* __restrict__ rstd) {
  int c = blockIdx.x * 256 + threadIdx.x;
  if (c >= HID_) return;
  float s = 0.f, s2 = 0.f;
  for (int i = 0; i < NS2_; ++i) { s += pS[i * HID_ + c]; s2 += pS2[i * HID_ + c]; }
  float m = s / B_;
  float v = s2 / B_ - m * m;
  mean[c] = m;
  rstd[c] = rsqrtf(v + EPS_);
}

// ---------------- BN2 apply + LeakyReLU(0.1) -> bf16 ----------------
__global__ __launch_bounds__(256) void bn2_apply_kernel(
    const float* __restrict__ Z, const float* __restrict__ mean, const float* __restrict__ rstd,
    const float* __restrict__ g, const float* __restrict__ bb, unsigned short* __restrict__ R) {
  int i = blockIdx.x * 256 + threadIdx.x;
  int c = i & (HID_ - 1);
  float v = (Z[i] - mean[c]) * rstd[c] * g[c] + bb[c];
  v = v > 0.f ? v : 0.1f * v;
  R[i] = f2bf_rne(v);
}

// ---------------- classifier with fused W2 split-K combine ----------------
__global__ __launch_bounds__(256) void classifier_kernel(
    const float* __restrict__ Cpart, const float* __restrict__ b2,
    const float* __restrict__ Wc, const float* __restrict__ bc,
    float* __restrict__ reg_out, float* __restrict__ ypred) {
  int b = blockIdx.x;
  __shared__ __align__(16) float rrow[NREG_];
  __shared__ float sl[256];
  int tid = threadIdx.x;
  for (int i = tid; i < NREG_; i += 256) {
    float s = b2[i];
#pragma unroll
    for (int z = 0; z < 4; ++z) s += Cpart[((size_t)z * B_ + b) * NREG_ + i];
    rrow[i] = s;
    reg_out[(size_t)b * NREG_ + i] = s;
  }
  __syncthreads();
  float s = -1e30f;
  if (tid < NCLS_) {
    const float* w = Wc + (size_t)tid * NREG_;
    float acc = 0.f;
    for (int k = 0; k < NREG_; k += 4) {
      float4 wv = *(const float4*)(w + k);
      float4 rv = *(const float4*)(&rrow[k]);
      acc = fmaf(wv.x, rv.x, acc); acc = fmaf(wv.y, rv.y, acc);
      acc = fmaf(wv.z, rv.z, acc); acc = fmaf(wv.w, rv.w, acc);
    }
    s = acc + bc[tid];
  }
  sl[tid] = s;
  __syncthreads();
  for (int o = 128; o > 0; o >>= 1) {
    if (tid < o) sl[tid] = fmaxf(sl[tid], sl[tid + o]);
    __syncthreads();
  }
  float mx = sl[0];
  __syncthreads();
  float e = (tid < NCLS_) ? __expf(s - mx) : 0.f;
  sl[tid] = e;
  __syncthreads();
  for (int o = 128; o > 0; o >>= 1) {
    if (tid < o) sl[tid] += sl[tid + o];
    __syncthreads();
  }
  if (tid < NCLS_) ypred[(size_t)b * NCLS_ + tid] = e / sl[0];
}

// ---------------- host orchestration ----------------
extern "C" void kernel_launch(void* const* d_in, const int* in_sizes, int n_in,
                              void* d_out, int out_size, void* d_ws, size_t ws_size,
                              hipStream_t stream) {
  const float* x     = (const float*)d_in[0];
  const float* enc_W = (const float*)d_in[1];
  const float* enc_b = (const float*)d_in[2];
  const float* bn1_g = (const float*)d_in[3];
  const float* bn1_b = (const float*)d_in[4];
  const float* Wqkv  = (const float*)d_in[5];
  const float* bqkv  = (const float*)d_in[6];
  const float* Wo    = (const float*)d_in[7];
  const float* bo    = (const float*)d_in[8];
  const float* W1    = (const float*)d_in[9];
  const float* b1    = (const float*)d_in[10];
  const float* bn2_g = (const float*)d_in[11];
  const float* bn2_b = (const float*)d_in[12];
  const float* W2    = (const float*)d_in[13];
  const float* b2    = (const float*)d_in[14];
  const float* Wc    = (const float*)d_in[15];
  const float* bc    = (const float*)d_in[16];

  char* ws = (char*)d_ws;
  size_t off = 0;
  auto alloc = [&](size_t bytes) -> void* {
    void* p = ws + off;
    off += (bytes + 255) & ~(size_t)255;
    return p;
  };

  unsigned short* yT     = (unsigned short*)alloc((size_t)CONCAT_ * B_ * 2); // bf16; reused for Z(f32)
  float*          mean1  = (float*)alloc(CONCAT_ * 4);
  float*          rstd1  = (float*)alloc(CONCAT_ * 4);
  unsigned short* Ybf    = (unsigned short*)alloc((size_t)B_ * E_ * 2);
  unsigned short* Rbf    = (unsigned short*)alloc((size_t)B_ * HID_ * 2);
  unsigned short* WoT_bf = (unsigned short*)alloc((size_t)E_ * E_ * 2);
  unsigned short* WvT_bf = (unsigned short*)alloc((size_t)E_ * E_ * 2);
  unsigned short* W1_bf  = (unsigned short*)alloc((size_t)HID_ * E_ * 2);
  unsigned short* W2_bf  = (unsigned short*)alloc((size_t)NREG_ * HID_ * 2);
  unsigned short* Wa_bf  = (unsigned short*)alloc((size_t)HID_ * E_ * 2);
  unsigned short* Wb_bf  = (unsigned short*)alloc((size_t)HID_ * E_ * 2);
  unsigned short* Wpk    = (unsigned short*)alloc((size_t)R_ * 2048 * 2);
  float*          Cpart  = (float*)alloc((size_t)4 * B_ * HID_ * 4);
  float*          t1v    = (float*)alloc(E_ * 4);
  float*          zbv    = (float*)alloc(HID_ * 4);
  float*          partS  = (float*)alloc((size_t)NS2_ * HID_ * 4);
  float*          partS2 = (float*)alloc((size_t)NS2_ * HID_ * 4);
  float*          mean2  = (float*)alloc(HID_ * 4);
  float*          rstd2  = (float*)alloc(HID_ * 4);
  int*            starts = (int*)alloc(R_ * 4);
  int*            redst  = (int*)alloc(R_ * 4);

  float* Z = (float*)yT;   // yT dead after bn1_transpose

  // K1: layout
  layout_kernel<<<1, 1, 0, stream>>>(starts, redst);
  // K2: prep — transposes || casts || rowdot1 || pack_w
  prep_kernel<<<2 * NTR_ + NCAST_ + E_ / 4 + R_, 256, 0, stream>>>(
      Wo, Wqkv + (size_t)2 * E_ * E_, WoT_bf, WvT_bf,
      W1, W1_bf, W2, W2_bf, bqkv + 2 * E_, bo, t1v, enc_W, starts, Wpk);
  // K3: Wa gemm || encode rows 0..1023 || rowdot2
  mega_a_kernel<<<WA_NB_ + ENCH_NB_ + HID_ / 4, 256, 0, stream>>>(
      x, Wpk, enc_b, starts, redst, yT, W1_bf, WoT_bf, Wa_bf, W1, t1v, b1, zbv);
  // K4: Wb gemm (KS2) || encode rows 1024..2047
  mega_b_kernel<<<WB2_NB_ + ENCH_NB_, 256, 0, stream>>>(
      x, Wpk, enc_b, starts, redst, yT, Wa_bf, WvT_bf, Cpart);
  // K5: bn1_stats || combine Wb -> bf16
  stats_comb_kernel<<<ST_NB_ + CWB_NB_, 256, 0, stream>>>(
      yT, mean1, rstd1, Cpart, Wb_bf);
  // K6: bn1 apply + transpose + pad -> Y
  bn1_transpose_kernel<<<TR_NB_, 256, 0, stream>>>(
      yT, mean1, rstd1, bn1_g, bn1_b, Ybf);
  // K7: Z = Y @ Wb^T (KS=4)
  gemm_kernel<4, false><<<dim3(HID_ / 128, B_ / 128, 4), 256, 0, stream>>>(
      Ybf, Wb_bf, Cpart, nullptr, B_, HID_, E_);
  // K8: Z combine + zb + BN2 partial stats
  combZ_stats_kernel<<<dim3(HID_ / 256, NS2_), 256, 0, stream>>>(Cpart, zbv, Z, partS, partS2);
  // K9: BN2 stats finalize
  colstats_final_kernel<<<(HID_ + 255) / 256, 256, 0, stream>>>(partS, partS2, mean2, rstd2);
  // K10: BN2 apply -> bf16
  bn2_apply_kernel<<<(B_ * HID_) / 256, 256, 0, stream>>>(Z, mean2, rstd2, bn2_g, bn2_b, Rbf);
  // K11: reg partials: R @ W2^T (KS=4)
  gemm_kernel<4, false><<<dim3((NREG_ + 127) / 128, B_ / 128, 4), 256, 0, stream>>>(
      Rbf, W2_bf, Cpart, nullptr, B_, NREG_, HID_);
  // K12: classifier (fused W2 combine) -> reg_out, y_pred
  float* reg_out = (float*)d_out;
  classifier_kernel<<<B_, 256, 0, stream>>>(
      Cpart, b2, Wc, bc, reg_out, reg_out + (size_t)B_ * NREG_);
}